// Round 25
// baseline (98.316 us; speedup 1.0000x reference)
//
#include <hip/hip_runtime.h>
#include <hip/hip_bf16.h>

// Block-sparse attention: B=2, S=4096, H=16, D=128, BS=64, LOCAL=8, GLOBAL=1.
// fp32 in/out, bf16 MFMA, flash softmax in exp2 domain (static max).
// Round 25 (base r22 = 92.3us): peel the diagonal tile (it is ALWAYS the last
// kv-tile) out of the main loop. Main loop loses the mask branch; the peeled
// tile exploits mask structure wave-uniformly: QK subtile n skipped for
// n > wave (24/64 MFMAs), softmax/pack skipped for masked subtiles (ch=0),
// PV kk=1 skipped for waves 0-1 (16/64 MFMAs). Everything else = r22.

typedef __bf16 bf16_t;
typedef bf16_t bf16x8 __attribute__((ext_vector_type(8)));
typedef float f32x4 __attribute__((ext_vector_type(4)));
typedef uint32_t u32x4 __attribute__((ext_vector_type(4)));

#define BSZ 64
#define DIM 128
#define NH 16
#define SEQ 4096
#define ROWSTRIDE (NH * DIM)

// LDS barrier with lgkm-only drain (global loads may stay in flight).
#define LGKM_BARRIER()                                          \
    do {                                                        \
        asm volatile("s_waitcnt lgkmcnt(0)" ::: "memory");      \
        __builtin_amdgcn_s_barrier();                           \
    } while (0)

__device__ __forceinline__ uint32_t cvt_pk_bf16(float lo, float hi) {
    uint32_t r;
    asm("v_cvt_pk_bf16_f32 %0, %1, %2" : "=v"(r) : "v"(lo), "v"(hi));
    return r;
}

// Kb: [64][128] bf16, A = row*256 + col*2. Rank-5 swizzle (r22).
__device__ __forceinline__ uint32_t kb_swz(uint32_t A) {
    return A ^ (((A >> 8) & 7u) << 4) ^ (((A >> 11) & 1u) << 7);
}
// Vt: [128][64] bf16, A = d*128 + k*2. Rank-5 swizzle (r22).
__device__ __forceinline__ uint32_t vt_swz(uint32_t A) {
    return A ^ (((A >> 9) & 7u) << 4) ^ (((A >> 9) & 1u) << 6) ^ (((A >> 12) & 3u) << 7);
}

__global__ __launch_bounds__(256) void sparse_attn_kernel(
    const float* __restrict__ q, const float* __restrict__ k,
    const float* __restrict__ v, float* __restrict__ out)
{
    __shared__ __align__(16) bf16_t Kb[BSZ * DIM];      // 16384 B
    __shared__ __align__(16) bf16_t Vt[DIM * BSZ];      // 16384 B (total 32768)

    // XCD-aware swizzle: 2048 wgs, 8 XCDs -> contiguous 256-chunk per XCD.
    const int L  = ((blockIdx.x & 7) << 8) | (blockIdx.x >> 3);
    const int qi = L & 63;
    const int h  = (L >> 6) & 15;
    const int b  = L >> 10;

    const int tid  = threadIdx.x;
    const int wave = tid >> 6;
    const int lane = tid & 63;
    const int lr = lane & 15;
    const int lk = lane >> 4;
    const int k0 = lk * 8;

    const int krr = tid >> 4;   // K staging: row-in-group 0..15
    const int kc8 = tid & 15;   // K staging: 8-float chunk 0..15
    const int vr  = tid >> 5;   // V staging: 8-row group 0..7
    const int sc4 = tid & 31;   // V staging: float4 column 0..31

    const float scale2 = 0.12751649736230476f;  // (1/sqrt(128)) * log2(e)

    const size_t bh_off = ((size_t)b * SEQ * NH + (size_t)h) * DIM;
    const float* kbh = k + bh_off;
    const float* vbh = v + bh_off;

    // ---- Q fragments, pre-scaled (wave owns q rows [qi*64+wave*16, +16)) ----
    bf16x8 qf[4];
    {
        const float* qrow = q + bh_off + (size_t)(qi * 64 + wave * 16 + lr) * ROWSTRIDE;
        #pragma unroll
        for (int kk = 0; kk < 4; ++kk) {
            const float4 a0 = *(const float4*)(qrow + 32 * kk + k0);
            const float4 a1 = *(const float4*)(qrow + 32 * kk + k0 + 4);
            u32x4 w = {cvt_pk_bf16(a0.x * scale2, a0.y * scale2),
                       cvt_pk_bf16(a0.z * scale2, a0.w * scale2),
                       cvt_pk_bf16(a1.x * scale2, a1.y * scale2),
                       cvt_pk_bf16(a1.z * scale2, a1.w * scale2)};
            qf[kk] = *(bf16x8*)&w;
        }
    }

    f32x4 oacc[8];
    #pragma unroll
    for (int n = 0; n < 8; ++n) oacc[n] = (f32x4){0.f, 0.f, 0.f, 0.f};
    float lrun = 0.f;   // per-lane partial row-sum; this lane's q-row is lr

    const int nnz = (qi < 8) ? (qi + 1) : 9;

    // ---- push-exchange addressing (constant per lane) ----
    const int bit0 = lk & 1;
    const int bit1 = lk >> 1;
    const bool hi  = (lk & 2) != 0;
    const int Dlo  = (lr + 16 * bit1) << 2;
    const int Dhi  = Dlo + (32 << 2);
    const int addrA = bit0 ? Dhi : Dlo;
    const int addrB = bit0 ? Dlo : Dhi;

    float4 kreg[8];   // K row (16i+krr), floats 8*kc8..+7
    float4 vreg[8];   // V rows 8*vr..+7, floats 4*sc4..+3

    #define LOAD_K(jb)                                                            \
    {                                                                             \
        _Pragma("unroll")                                                         \
        for (int i = 0; i < 4; ++i) {                                             \
            const float* p_ = kbh + (size_t)((jb) * 64 + 16 * i + krr) * ROWSTRIDE\
                              + 8 * kc8;                                          \
            kreg[2 * i]     = *(const float4*)(p_);                               \
            kreg[2 * i + 1] = *(const float4*)(p_ + 4);                           \
        }                                                                         \
    }
    #define LOAD_V(jb)                                                            \
    {                                                                             \
        const float* vb_ = vbh + (size_t)((jb) * 64 + 8 * vr) * ROWSTRIDE + 4 * sc4;\
        _Pragma("unroll")                                                         \
        for (int i = 0; i < 8; ++i)                                               \
            vreg[i] = *(const float4*)(vb_ + (size_t)i * ROWSTRIDE);              \
    }
    #define KB_WRITE()                                                            \
    {                                                                             \
        _Pragma("unroll")                                                         \
        for (int i = 0; i < 4; ++i) {                                             \
            const float4 a0 = kreg[2 * i];                                        \
            const float4 a1 = kreg[2 * i + 1];                                    \
            u32x4 w = {cvt_pk_bf16(a0.x, a0.y), cvt_pk_bf16(a0.z, a0.w),          \
                       cvt_pk_bf16(a1.x, a1.y), cvt_pk_bf16(a1.z, a1.w)};         \
            const uint32_t A = kb_swz((uint32_t)((16 * i + krr) * 256 + 16 * kc8));\
            *(u32x4*)((char*)Kb + A) = w;                                         \
        }                                                                         \
    }
    #define VT_WRITE()                                                            \
    {                                                                             \
        _Pragma("unroll")                                                         \
        for (int j2 = 0; j2 < 4; ++j2) {                                          \
            u32x4 w = {cvt_pk_bf16(((const float*)&vreg[0])[j2],                  \
                                   ((const float*)&vreg[1])[j2]),                 \
                       cvt_pk_bf16(((const float*)&vreg[2])[j2],                  \
                                   ((const float*)&vreg[3])[j2]),                 \
                       cvt_pk_bf16(((const float*)&vreg[4])[j2],                  \
                                   ((const float*)&vreg[5])[j2]),                 \
                       cvt_pk_bf16(((const float*)&vreg[6])[j2],                  \
                                   ((const float*)&vreg[7])[j2])};                \
            const int d = 4 * sc4 + j2;                                           \
            const uint32_t A = vt_swz((uint32_t)(d * 128 + 16 * vr));             \
            *(u32x4*)((char*)Vt + A) = w;                                         \
        }                                                                         \
    }
    // exchange: ch[8] -> paf[2]
    #define EXCHANGE(ch, paf)                                                     \
    {                                                                             \
        _Pragma("unroll")                                                         \
        for (int kk = 0; kk < 2; ++kk) {                                          \
            uint32_t r0 = (uint32_t)__builtin_amdgcn_ds_permute(                  \
                addrA, (int)(bit0 ? ch[4 * kk + 2] : ch[4 * kk + 0]));            \
            uint32_t r1 = (uint32_t)__builtin_amdgcn_ds_permute(                  \
                addrA, (int)(bit0 ? ch[4 * kk + 3] : ch[4 * kk + 1]));            \
            uint32_t r2 = (uint32_t)__builtin_amdgcn_ds_permute(                  \
                addrB, (int)(bit0 ? ch[4 * kk + 0] : ch[4 * kk + 2]));            \
            uint32_t r3 = (uint32_t)__builtin_amdgcn_ds_permute(                  \
                addrB, (int)(bit0 ? ch[4 * kk + 1] : ch[4 * kk + 3]));            \
            u32x4 tv = {hi ? r2 : r0, hi ? r3 : r1,                               \
                        hi ? r0 : r2, hi ? r1 : r3};                              \
            paf[kk] = *(bf16x8*)&tv;                                              \
        }                                                                         \
    }

    LOAD_K(0);  // j_of(0) == 0 for every qi
    LOAD_V(0);

    // ================= main loop: non-diagonal tiles (no mask) =================
    for (int t = 0; t < nnz - 1; ++t) {
        const int jn = (qi < 8) ? (t + 1) : (qi - 8 + t + 1);

        KB_WRITE();
        LOAD_K(jn);                       // kreg dead: full-iter cover
        LGKM_BARRIER();                   // Kb visible; loads stay in flight

        f32x4 sacc[4];
        #pragma unroll
        for (int n = 0; n < 4; ++n) {
            f32x4 a = (f32x4){0.f, 0.f, 0.f, 0.f};
            #pragma unroll
            for (int kk = 0; kk < 4; ++kk) {
                const uint32_t A = kb_swz((uint32_t)((16 * n + lr) * 256 + 64 * kk + 16 * lk));
                bf16x8 kf = *(const bf16x8*)((const char*)Kb + A);
                a = __builtin_amdgcn_mfma_f32_16x16x32_bf16(kf, qf[kk], a, 0, 0, 0);
            }
            sacc[n] = a;
        }

        VT_WRITE();
        LOAD_V(jn);                       // vreg dead: full-iter cover

        uint32_t ch[8];
        #pragma unroll
        for (int n = 0; n < 4; ++n) {
            float p0 = exp2f(sacc[n][0]);
            float p1 = exp2f(sacc[n][1]);
            float p2 = exp2f(sacc[n][2]);
            float p3 = exp2f(sacc[n][3]);
            lrun += (p0 + p1) + (p2 + p3);
            ch[2 * n]     = cvt_pk_bf16(p0, p1);
            ch[2 * n + 1] = cvt_pk_bf16(p2, p3);
        }

        bf16x8 paf[2];
        EXCHANGE(ch, paf);

        LGKM_BARRIER();                   // Vt visible + Kb reads done

        #pragma unroll
        for (int n = 0; n < 8; ++n) {
            f32x4 a = oacc[n];
            #pragma unroll
            for (int kk = 0; kk < 2; ++kk) {
                const uint32_t Av = vt_swz((uint32_t)((16 * n + lr) * 128 + 64 * kk + 16 * lk));
                bf16x8 vf = *(const bf16x8*)((const char*)Vt + Av);
                a = __builtin_amdgcn_mfma_f32_16x16x32_bf16(paf[kk], vf, a, 0, 0, 0);
            }
            oacc[n] = a;
        }
    }

    // ================= peeled diagonal tile (j == qi) =================
    {
        KB_WRITE();
        LGKM_BARRIER();

        // QK only for k-subtiles n <= wave (n > wave fully masked)
        f32x4 sacc[4];
        #pragma unroll
        for (int n = 0; n < 4; ++n) {
            if (n <= wave) {              // wave-uniform
                f32x4 a = (f32x4){0.f, 0.f, 0.f, 0.f};
                #pragma unroll
                for (int kk = 0; kk < 4; ++kk) {
                    const uint32_t A = kb_swz((uint32_t)((16 * n + lr) * 256 + 64 * kk + 16 * lk));
                    bf16x8 kf = *(const bf16x8*)((const char*)Kb + A);
                    a = __builtin_amdgcn_mfma_f32_16x16x32_bf16(kf, qf[kk], a, 0, 0, 0);
                }
                sacc[n] = a;
            }
        }

        VT_WRITE();

        // softmax: n < wave unmasked, n == wave triangular (4lk+r > lr masked),
        // n > wave all-zero
        uint32_t ch[8] = {0u, 0u, 0u, 0u, 0u, 0u, 0u, 0u};
        #pragma unroll
        for (int n = 0; n < 4; ++n) {
            if (n < wave) {
                float p0 = exp2f(sacc[n][0]);
                float p1 = exp2f(sacc[n][1]);
                float p2 = exp2f(sacc[n][2]);
                float p3 = exp2f(sacc[n][3]);
                lrun += (p0 + p1) + (p2 + p3);
                ch[2 * n]     = cvt_pk_bf16(p0, p1);
                ch[2 * n + 1] = cvt_pk_bf16(p2, p3);
            } else if (n == wave) {
                float p0 = (4 * lk + 0 > lr) ? 0.f : exp2f(sacc[n][0]);
                float p1 = (4 * lk + 1 > lr) ? 0.f : exp2f(sacc[n][1]);
                float p2 = (4 * lk + 2 > lr) ? 0.f : exp2f(sacc[n][2]);
                float p3 = (4 * lk + 3 > lr) ? 0.f : exp2f(sacc[n][3]);
                lrun += (p0 + p1) + (p2 + p3);
                ch[2 * n]     = cvt_pk_bf16(p0, p1);
                ch[2 * n + 1] = cvt_pk_bf16(p2, p3);
            }
        }

        bf16x8 paf[2];
        EXCHANGE(ch, paf);

        LGKM_BARRIER();

        // PV: paf[1] (k >= 32) is all-zero for waves 0-1 -> skip those MFMAs
        #pragma unroll
        for (int n = 0; n < 8; ++n) {
            const uint32_t Av = vt_swz((uint32_t)((16 * n + lr) * 128 + 16 * lk));
            bf16x8 vf = *(const bf16x8*)((const char*)Vt + Av);
            oacc[n] = __builtin_amdgcn_mfma_f32_16x16x32_bf16(paf[0], vf, oacc[n], 0, 0, 0);
        }
        if (wave >= 2) {                  // wave-uniform
            #pragma unroll
            for (int n = 0; n < 8; ++n) {
                const uint32_t Av = vt_swz((uint32_t)((16 * n + lr) * 128 + 64 + 16 * lk));
                bf16x8 vf = *(const bf16x8*)((const char*)Vt + Av);
                oacc[n] = __builtin_amdgcn_mfma_f32_16x16x32_bf16(paf[1], vf, oacc[n], 0, 0, 0);
            }
        }
    }

    // ---- epilogue: total l per q-row, redistribute to oacc rows, store ----
    float lrtot = lrun;
    lrtot += __shfl_xor(lrtot, 16);
    lrtot += __shfl_xor(lrtot, 32);
    float* obase = out + bh_off + (size_t)(qi * 64 + wave * 16) * ROWSTRIDE;
    #pragma unroll
    for (int r = 0; r < 4; ++r) {
        const float inv = 1.0f / __shfl(lrtot, 4 * lk + r);
        float* orow = obase + (size_t)(4 * lk + r) * ROWSTRIDE;
        #pragma unroll
        for (int n = 0; n < 8; ++n) {
            orow[16 * n + lr] = oacc[n][r] * inv;
        }
    }
}

extern "C" void kernel_launch(void* const* d_in, const int* in_sizes, int n_in,
                              void* d_out, int out_size, void* d_ws, size_t ws_size,
                              hipStream_t stream) {
    const float* q = (const float*)d_in[0];
    const float* k = (const float*)d_in[1];
    const float* v = (const float*)d_in[2];
    float* out = (float*)d_out;
    sparse_attn_kernel<<<dim3(2048), dim3(256), 0, stream>>>(q, k, v, out);
}

// Round 26
// 92.775 us; speedup vs baseline: 1.0597x; 1.0597x over previous
//
#include <hip/hip_runtime.h>
#include <hip/hip_bf16.h>

// Block-sparse attention: B=2, S=4096, H=16, D=128, BS=64, LOCAL=8, GLOBAL=1.
// fp32 in/out, bf16 MFMA, flash softmax in exp2 domain (static max).
// Round 26: REVERT to r22 (92.3us, session best). r23 (producer-consumer),
// r24 (barrier halving), r25 (diag peel) all regressed — in this latency-bound
// regime anything that grows code/registers loses more than it saves.
// r22 = swapped QK^T + in-reg softmax + push ds_permute exchange + rank-5
// swizzles + dead-zone reg prefetch + lgkm-only barriers + cvt_pk + b128
// staging + XCD swizzle; no setprio, no sched_barrier.

typedef __bf16 bf16_t;
typedef bf16_t bf16x8 __attribute__((ext_vector_type(8)));
typedef float f32x4 __attribute__((ext_vector_type(4)));
typedef uint32_t u32x4 __attribute__((ext_vector_type(4)));

#define BSZ 64
#define DIM 128
#define NH 16
#define SEQ 4096
#define ROWSTRIDE (NH * DIM)

// LDS barrier with lgkm-only drain (global loads may stay in flight).
#define LGKM_BARRIER()                                          \
    do {                                                        \
        asm volatile("s_waitcnt lgkmcnt(0)" ::: "memory");      \
        __builtin_amdgcn_s_barrier();                           \
    } while (0)

// packed f32x2 -> bf16x2 (RNE), result word: low16=lo, high16=hi
__device__ __forceinline__ uint32_t cvt_pk_bf16(float lo, float hi) {
    uint32_t r;
    asm("v_cvt_pk_bf16_f32 %0, %1, %2" : "=v"(r) : "v"(lo), "v"(hi));
    return r;
}

// Kb: [64][128] bf16, A = row*256 + col*2. Rank-5 swizzle: slot bits
// {lk0^lr0, lk1^lr1, kk0^lr2, kk1^lr3, lr0} -> 2-way on all access patterns.
__device__ __forceinline__ uint32_t kb_swz(uint32_t A) {
    return A ^ (((A >> 8) & 7u) << 4) ^ (((A >> 11) & 1u) << 7);
}
// Vt: [128][64] bf16, A = d*128 + k*2. Rank-5 swizzle: read slot
// {lr0, lr1, lk0^lr2, lk1^lr3, lr2}; write side spreads sc4 bits -> 2-way.
__device__ __forceinline__ uint32_t vt_swz(uint32_t A) {
    return A ^ (((A >> 9) & 7u) << 4) ^ (((A >> 9) & 1u) << 6) ^ (((A >> 12) & 3u) << 7);
}

__global__ __launch_bounds__(256) void sparse_attn_kernel(
    const float* __restrict__ q, const float* __restrict__ k,
    const float* __restrict__ v, float* __restrict__ out)
{
    __shared__ __align__(16) bf16_t Kb[BSZ * DIM];      // 16384 B
    __shared__ __align__(16) bf16_t Vt[DIM * BSZ];      // 16384 B (total 32768)

    // XCD-aware swizzle: 2048 wgs, 8 XCDs -> contiguous 256-chunk per XCD.
    const int L  = ((blockIdx.x & 7) << 8) | (blockIdx.x >> 3);
    const int qi = L & 63;
    const int h  = (L >> 6) & 15;
    const int b  = L >> 10;

    const int tid  = threadIdx.x;
    const int wave = tid >> 6;
    const int lane = tid & 63;
    const int lr = lane & 15;
    const int lk = lane >> 4;
    const int k0 = lk * 8;

    const int krr = tid >> 4;   // K staging: row-in-group 0..15
    const int kc8 = tid & 15;   // K staging: 8-float chunk 0..15
    const int vr  = tid >> 5;   // V staging: 8-row group 0..7
    const int sc4 = tid & 31;   // V staging: float4 column 0..31

    const float scale2 = 0.12751649736230476f;  // (1/sqrt(128)) * log2(e)

    const size_t bh_off = ((size_t)b * SEQ * NH + (size_t)h) * DIM;
    const float* kbh = k + bh_off;
    const float* vbh = v + bh_off;

    // ---- Q fragments, pre-scaled (wave owns q rows [qi*64+wave*16, +16)) ----
    bf16x8 qf[4];
    {
        const float* qrow = q + bh_off + (size_t)(qi * 64 + wave * 16 + lr) * ROWSTRIDE;
        #pragma unroll
        for (int kk = 0; kk < 4; ++kk) {
            const float4 a0 = *(const float4*)(qrow + 32 * kk + k0);
            const float4 a1 = *(const float4*)(qrow + 32 * kk + k0 + 4);
            u32x4 w = {cvt_pk_bf16(a0.x * scale2, a0.y * scale2),
                       cvt_pk_bf16(a0.z * scale2, a0.w * scale2),
                       cvt_pk_bf16(a1.x * scale2, a1.y * scale2),
                       cvt_pk_bf16(a1.z * scale2, a1.w * scale2)};
            qf[kk] = *(bf16x8*)&w;
        }
    }

    f32x4 oacc[8];
    #pragma unroll
    for (int n = 0; n < 8; ++n) oacc[n] = (f32x4){0.f, 0.f, 0.f, 0.f};
    float lrun = 0.f;   // per-lane partial row-sum; this lane's q-row is lr

    const int qrow_local = wave * 16 + lr;  // q position within the 64-block
    const int nnz = (qi < 8) ? (qi + 1) : 9;

    // ---- push-exchange addressing (constant per lane) ----
    const int bit0 = lk & 1;
    const int bit1 = lk >> 1;
    const bool hi  = (lk & 2) != 0;
    const int Dlo  = (lr + 16 * bit1) << 2;   // dest-lane*4, hi_t = 0
    const int Dhi  = Dlo + (32 << 2);         // hi_t = 1
    const int addrA = bit0 ? Dhi : Dlo;       // instrs j = 0,1
    const int addrB = bit0 ? Dlo : Dhi;       // instrs j = 2,3

    float4 kreg[8];   // K row (16i+krr), floats 8*kc8..+7  (pairs per pass)
    float4 vreg[8];   // V rows 8*vr..+7, floats 4*sc4..+3

    #define LOAD_K(jb)                                                            \
    {                                                                             \
        _Pragma("unroll")                                                         \
        for (int i = 0; i < 4; ++i) {                                             \
            const float* p_ = kbh + (size_t)((jb) * 64 + 16 * i + krr) * ROWSTRIDE\
                              + 8 * kc8;                                          \
            kreg[2 * i]     = *(const float4*)(p_);                               \
            kreg[2 * i + 1] = *(const float4*)(p_ + 4);                           \
        }                                                                         \
    }
    #define LOAD_V(jb)                                                            \
    {                                                                             \
        const float* vb_ = vbh + (size_t)((jb) * 64 + 8 * vr) * ROWSTRIDE + 4 * sc4;\
        _Pragma("unroll")                                                         \
        for (int i = 0; i < 8; ++i)                                               \
            vreg[i] = *(const float4*)(vb_ + (size_t)i * ROWSTRIDE);              \
    }

    LOAD_K(0);  // j_of(0) == 0 for every qi
    LOAD_V(0);

    for (int t = 0; t < nnz; ++t) {
        const int j = (qi < 8) ? t : ((t == 0) ? 0 : (qi - 8 + t));
        const int jn = (qi < 8) ? (t + 1) : (qi - 8 + t + 1);
        const bool have_next = (t + 1 < nnz);

        // ---- Kb write from kreg: 4 x b128, cvt_pk converts ----
        #pragma unroll
        for (int i = 0; i < 4; ++i) {
            const float4 a0 = kreg[2 * i];
            const float4 a1 = kreg[2 * i + 1];
            u32x4 w = {cvt_pk_bf16(a0.x, a0.y), cvt_pk_bf16(a0.z, a0.w),
                       cvt_pk_bf16(a1.x, a1.y), cvt_pk_bf16(a1.z, a1.w)};
            const uint32_t A = kb_swz((uint32_t)((16 * i + krr) * 256 + 16 * kc8));
            *(u32x4*)((char*)Kb + A) = w;
        }
        // ---- kreg dead: issue next K loads NOW (full-iter cover) ----
        if (have_next) { LOAD_K(jn); }

        LGKM_BARRIER();   // Kb visible; K(t+1)/V(t) loads stay in flight

        // ---- S^T = K*Q^T: lane holds S[k=16n+4lk+r][q=lr] (exp2 domain) ----
        f32x4 sacc[4];
        #pragma unroll
        for (int n = 0; n < 4; ++n) {
            f32x4 a = (f32x4){0.f, 0.f, 0.f, 0.f};
            #pragma unroll
            for (int kk = 0; kk < 4; ++kk) {
                const uint32_t A = kb_swz((uint32_t)((16 * n + lr) * 256 + 64 * kk + 16 * lk));
                bf16x8 kf = *(const bf16x8*)((const char*)Kb + A);
                a = __builtin_amdgcn_mfma_f32_16x16x32_bf16(kf, qf[kk], a, 0, 0, 0);
            }
            sacc[n] = a;
        }

        // ---- Vt write from vreg: transposed, 4 x b128, cvt_pk converts ----
        #pragma unroll
        for (int j2 = 0; j2 < 4; ++j2) {
            u32x4 w = {cvt_pk_bf16(((const float*)&vreg[0])[j2], ((const float*)&vreg[1])[j2]),
                       cvt_pk_bf16(((const float*)&vreg[2])[j2], ((const float*)&vreg[3])[j2]),
                       cvt_pk_bf16(((const float*)&vreg[4])[j2], ((const float*)&vreg[5])[j2]),
                       cvt_pk_bf16(((const float*)&vreg[6])[j2], ((const float*)&vreg[7])[j2])};
            const int d = 4 * sc4 + j2;
            const uint32_t A = vt_swz((uint32_t)(d * 128 + 16 * vr));
            *(u32x4*)((char*)Vt + A) = w;
        }
        // ---- vreg dead: issue next V loads NOW (full-iter cover) ----
        if (have_next) { LOAD_V(jn); }

        // ---- mask (diag only) ----
        if (j == qi) {
            #pragma unroll
            for (int n = 0; n < 4; ++n)
                #pragma unroll
                for (int r = 0; r < 4; ++r) {
                    if (16 * n + 4 * lk + r > qrow_local) sacc[n][r] = -1.0e30f;
                }
        }

        // ---- static-max softmax: p = 2^s; cvt_pk output IS the chunk word ----
        uint32_t ch[8];
        #pragma unroll
        for (int n = 0; n < 4; ++n) {
            float p0 = exp2f(sacc[n][0]);
            float p1 = exp2f(sacc[n][1]);
            float p2 = exp2f(sacc[n][2]);
            float p3 = exp2f(sacc[n][3]);
            lrun += (p0 + p1) + (p2 + p3);
            ch[2 * n]     = cvt_pk_bf16(p0, p1);
            ch[2 * n + 1] = cvt_pk_bf16(p2, p3);
        }

        // ---- push-model exchange: paf[kk] = P[q=lr][k=32kk+8lk..+7] ----
        bf16x8 paf[2];
        #pragma unroll
        for (int kk = 0; kk < 2; ++kk) {
            uint32_t r0 = (uint32_t)__builtin_amdgcn_ds_permute(
                addrA, (int)(bit0 ? ch[4 * kk + 2] : ch[4 * kk + 0]));
            uint32_t r1 = (uint32_t)__builtin_amdgcn_ds_permute(
                addrA, (int)(bit0 ? ch[4 * kk + 3] : ch[4 * kk + 1]));
            uint32_t r2 = (uint32_t)__builtin_amdgcn_ds_permute(
                addrB, (int)(bit0 ? ch[4 * kk + 0] : ch[4 * kk + 2]));
            uint32_t r3 = (uint32_t)__builtin_amdgcn_ds_permute(
                addrB, (int)(bit0 ? ch[4 * kk + 1] : ch[4 * kk + 3]));
            u32x4 tv = {hi ? r2 : r0, hi ? r3 : r1,
                        hi ? r0 : r2, hi ? r1 : r3};
            paf[kk] = *(bf16x8*)&tv;
        }

        LGKM_BARRIER();   // Vt visible + this wave's Kb reads done

        // ---- O += P * V ----
        #pragma unroll
        for (int n = 0; n < 8; ++n) {
            f32x4 a = oacc[n];
            #pragma unroll
            for (int kk = 0; kk < 2; ++kk) {
                const uint32_t Av = vt_swz((uint32_t)((16 * n + lr) * 128 + 64 * kk + 16 * lk));
                bf16x8 vf = *(const bf16x8*)((const char*)Vt + Av);
                a = __builtin_amdgcn_mfma_f32_16x16x32_bf16(paf[kk], vf, a, 0, 0, 0);
            }
            oacc[n] = a;
        }
    }

    // ---- epilogue: total l per q-row, redistribute to oacc rows, store ----
    float lrtot = lrun;
    lrtot += __shfl_xor(lrtot, 16);
    lrtot += __shfl_xor(lrtot, 32);
    float* obase = out + bh_off + (size_t)(qi * 64 + wave * 16) * ROWSTRIDE;
    #pragma unroll
    for (int r = 0; r < 4; ++r) {
        const float inv = 1.0f / __shfl(lrtot, 4 * lk + r);
        float* orow = obase + (size_t)(4 * lk + r) * ROWSTRIDE;
        #pragma unroll
        for (int n = 0; n < 8; ++n) {
            orow[16 * n + lr] = oacc[n][r] * inv;
        }
    }
}

extern "C" void kernel_launch(void* const* d_in, const int* in_sizes, int n_in,
                              void* d_out, int out_size, void* d_ws, size_t ws_size,
                              hipStream_t stream) {
    const float* q = (const float*)d_in[0];
    const float* k = (const float*)d_in[1];
    const float* v = (const float*)d_in[2];
    float* out = (float*)d_out;
    sparse_attn_kernel<<<dim3(2048), dim3(256), 0, stream>>>(q, k, v, out);
}